// Round 16
// baseline (226.393 us; speedup 1.0000x reference)
//
#include <hip/hip_runtime.h>
#include <hip/hip_bf16.h>
#include <hip/hip_fp8.h>
#include <stdint.h>

#define Nn 8192
#define TWO_N 16384
#define INV_TAU 2.0f
// exp(x/TAU) = exp2(x * 2.885390); sqrt(2.885390) is folded into the stored
// fp8 vectors so the Gram epilogue is a bare exp2 (no per-element mul).
#define SQRT_E2S 1.6986436f      /* sqrt(2.885390081777927) */
#define LN2f 0.69314718f

typedef unsigned short u16;
typedef unsigned char u8;
typedef __bf16 bf16x8 __attribute__((ext_vector_type(8)));
typedef float f32x4 __attribute__((ext_vector_type(4)));
typedef int i32x8 __attribute__((ext_vector_type(8)));

typedef const __attribute__((address_space(1))) void* gas_ptr;
typedef __attribute__((address_space(3))) void* las_ptr;

__device__ __forceinline__ void async_copy16(const void* g, void* l) {
  __builtin_amdgcn_global_load_lds((gas_ptr)g, (las_ptr)l, 16, 0, 0);
}

// v_exp_f32: D = 2^S0 (hardware transcendental)
__device__ __forceinline__ float hw_exp2(float x) {
  return __builtin_amdgcn_exp2f(x);
}

// ---------------- W f32 -> bf16 pre-convert (once, ~256 KB out) -------------
__global__ __launch_bounds__(256)
void wcvt(const float* __restrict__ W1, const float* __restrict__ W2,
          __bf16* __restrict__ Wb) {
  int i = (blockIdx.x * 256 + threadIdx.x) * 8;
  const float* s = (i < 65536) ? (W1 + i) : (W2 + (i - 65536));
  float4 a0 = *(const float4*)s, a1 = *(const float4*)(s + 4);
  bf16x8 v = {(__bf16)a0.x, (__bf16)a0.y, (__bf16)a0.z, (__bf16)a0.w,
              (__bf16)a1.x, (__bf16)a1.y, (__bf16)a1.z, (__bf16)a1.w};
  *(bf16x8*)&Wb[i] = v;
}

// ---------------- fused MLP + normalize + SCALED fp8 emit --------------------
// (R15 version verbatim -- verified: emitted fp8 = n * SQRT_E2S, snorm=||m||^2)
__global__ __launch_bounds__(256)
void mlp_norm(const float* __restrict__ z1, const float* __restrict__ z2,
              const __bf16* __restrict__ Wb, const float* __restrict__ b1,
              const float* __restrict__ b2,
              u8* __restrict__ Mf8, float* __restrict__ snorm,
              float* __restrict__ rsum) {
  __shared__ __bf16 sZ[64 * 64];    // 8 KB  (layer1 A; reduce scratch later)
  __shared__ __bf16 sW[256 * 64];   // 32 KB (W chunk, both layers)
  __shared__ __bf16 sH[64 * 256];   // 32 KB (H1, full K for layer 2)
  const int bx = blockIdx.x;
  const int i0 = bx * 64;
  const float* Zsrc = (bx < 128) ? (z1 + (size_t)i0 * 256)
                                 : (z2 + (size_t)(i0 - Nn) * 256);
  const int t = threadIdx.x;
  const int lane = t & 63, wave = t >> 6;
  const int wn = wave * 64;
  const int fr = lane >> 4, fc = lane & 15;
  const int sw = fc & 7;

  const __bf16* Wb1 = Wb;
  const __bf16* Wb2 = Wb + 65536;

  if (t < 64) rsum[i0 + t] = 0.f;

  f32x4 acc[4][4];
#pragma unroll
  for (int a = 0; a < 4; a++)
#pragma unroll
    for (int b = 0; b < 4; b++) acc[a][b] = (f32x4){0.f, 0.f, 0.f, 0.f};

  // ---- layer 1 ----
  for (int k0 = 0; k0 < 256; k0 += 64) {
    __syncthreads();
#pragma unroll
    for (int it = 0; it < 8; ++it) {               // W1: 2048 granules, async DMA
      int c = t + 256 * it;
      int row = c >> 3, g = (c & 7) ^ (row & 7);
      async_copy16(Wb1 + (size_t)row * 256 + k0 + g * 8, (void*)&sW[c * 8]);
    }
#pragma unroll
    for (int it = 0; it < 2; ++it) {               // Z: 512 granules (convert)
      int c = t + 256 * it;
      int row = c >> 3, g = (c & 7) ^ (row & 7);
      const float* s = Zsrc + (size_t)row * 256 + k0 + g * 8;
      float4 a0 = *(const float4*)s, a1 = *(const float4*)(s + 4);
      bf16x8 v = {(__bf16)a0.x, (__bf16)a0.y, (__bf16)a0.z, (__bf16)a0.w,
                  (__bf16)a1.x, (__bf16)a1.y, (__bf16)a1.z, (__bf16)a1.w};
      *(bf16x8*)&sZ[c * 8] = v;
    }
    __syncthreads();
#pragma unroll
    for (int ks = 0; ks < 2; ++ks) {
      bf16x8 af[4], bfr[4];
#pragma unroll
      for (int mi = 0; mi < 4; mi++)
        af[mi] = *(const bf16x8*)&sZ[(mi * 16 + fc) * 64 + (((ks * 4 + fr) ^ sw) * 8)];
#pragma unroll
      for (int ni = 0; ni < 4; ni++)
        bfr[ni] = *(const bf16x8*)&sW[(wn + ni * 16 + fc) * 64 + (((ks * 4 + fr) ^ sw) * 8)];
#pragma unroll
      for (int mi = 0; mi < 4; mi++)
#pragma unroll
        for (int ni = 0; ni < 4; ni++)
          acc[mi][ni] = __builtin_amdgcn_mfma_f32_16x16x32_bf16(af[mi], bfr[ni], acc[mi][ni], 0, 0, 0);
    }
  }

  // layer-1 epilogue: bias + elu -> bf16 into sH (granule-xor swizzled rows)
  {
    float bv[4];
#pragma unroll
    for (int ni = 0; ni < 4; ni++) bv[ni] = b1[wn + ni * 16 + fc];
#pragma unroll
    for (int mi = 0; mi < 4; mi++)
#pragma unroll
      for (int ni = 0; ni < 4; ni++) {
        int col = wn + ni * 16 + fc;
        int gc = col >> 3;
#pragma unroll
        for (int r = 0; r < 4; r++) {
          int row = mi * 16 + fr * 4 + r;
          float v = acc[mi][ni][r] + bv[ni];
          v = v > 0.f ? v : (__expf(v) - 1.f);
          int pos = (gc & 24) | ((gc & 7) ^ (row & 7));
          sH[row * 256 + pos * 8 + (col & 7)] = (__bf16)v;
          acc[mi][ni][r] = 0.f;
        }
      }
  }

  // ---- layer 2 (A = sH, resident full-K) ----
  for (int k0 = 0; k0 < 256; k0 += 64) {
    __syncthreads();   // also guarantees: all sH writes done before first read
#pragma unroll
    for (int it = 0; it < 8; ++it) {               // W2: 2048 granules, async DMA
      int c = t + 256 * it;
      int row = c >> 3, g = (c & 7) ^ (row & 7);
      async_copy16(Wb2 + (size_t)row * 256 + k0 + g * 8, (void*)&sW[c * 8]);
    }
    __syncthreads();
    const int kgb = k0 >> 3;
#pragma unroll
    for (int ks = 0; ks < 2; ++ks) {
      bf16x8 af[4], bfr[4];
#pragma unroll
      for (int mi = 0; mi < 4; mi++)
        af[mi] = *(const bf16x8*)&sH[(mi * 16 + fc) * 256 + (kgb + (((ks * 4 + fr) ^ sw))) * 8];
#pragma unroll
      for (int ni = 0; ni < 4; ni++)
        bfr[ni] = *(const bf16x8*)&sW[(wn + ni * 16 + fc) * 64 + (((ks * 4 + fr) ^ sw) * 8)];
#pragma unroll
      for (int mi = 0; mi < 4; mi++)
#pragma unroll
        for (int ni = 0; ni < 4; ni++)
          acc[mi][ni] = __builtin_amdgcn_mfma_f32_16x16x32_bf16(af[mi], bfr[ni], acc[mi][ni], 0, 0, 0);
    }
  }

  // ---- epilogue: bias, cross-wave row-norm, SCALED fp8 emit, snorm ----
  float bv[4];
#pragma unroll
  for (int ni = 0; ni < 4; ni++) bv[ni] = b2[wn + ni * 16 + fc];

  __syncthreads();                 // sZ dead; reuse as reduce scratch
  float* red = (float*)sZ;         // [64 rows][4 waves]
  float* red2 = red + 256;

#pragma unroll
  for (int mi = 0; mi < 4; mi++) {
    float ssq[4] = {0.f, 0.f, 0.f, 0.f};
#pragma unroll
    for (int ni = 0; ni < 4; ni++)
#pragma unroll
      for (int r = 0; r < 4; r++) {
        float v = acc[mi][ni][r] + bv[ni];
        acc[mi][ni][r] = v;
        ssq[r] += v * v;
      }
#pragma unroll
    for (int r = 0; r < 4; r++) {
      float v = ssq[r];
#pragma unroll
      for (int off = 1; off < 16; off <<= 1) v += __shfl_xor(v, off, 16);
      if (fc == 0) red[(mi * 16 + fr * 4 + r) * 4 + wave] = v;
    }
  }
  __syncthreads();

#pragma unroll
  for (int mi = 0; mi < 4; mi++) {
    float ssq2[4] = {0.f, 0.f, 0.f, 0.f};
#pragma unroll
    for (int r = 0; r < 4; r++) {
      int row = mi * 16 + fr * 4 + r;
      float ss = red[row * 4] + red[row * 4 + 1] + red[row * 4 + 2] + red[row * 4 + 3];
      float rn = SQRT_E2S / fmaxf(sqrtf(ss), 1e-12f);   // scale folded here
#pragma unroll
      for (int ni = 0; ni < 4; ni++) {
        float v = acc[mi][ni][r] * rn;
        __hip_fp8_e4m3 q(v);
        Mf8[(size_t)(i0 + row) * 256 + wn + ni * 16 + fc] = q.__x;
        float fv = (float)q;
        ssq2[r] += fv * fv;                              // snorm = ||m||^2
      }
    }
#pragma unroll
    for (int r = 0; r < 4; r++) {
      float v = ssq2[r];
#pragma unroll
      for (int off = 1; off < 16; off <<= 1) v += __shfl_xor(v, off, 16);
      if (fc == 0) red2[(mi * 16 + fr * 4 + r) * 4 + wave] = v;
    }
  }
  __syncthreads();
  if (t < 64)
    snorm[i0 + t] = red2[t * 4] + red2[t * 4 + 1] + red2[t * 4 + 2] + red2[t * 4 + 3];
}

// ---------------- symmetric Gram, MX fp8 K=128, no-LDS, UNCAPPED residency ---
// v10: R14's barrier-free/LDS-free body, but __launch_bounds__(256) with NO
// second arg. Discovery (R5/R6/R7/R11/R14 occupancy table): arg2 pins the
// resident-wave target (Occ% == arg2-proportional in every round, even R14's
// no-LDS kernel at VGPR 112 / LDS 0 sat at 2 blocks/CU). Removing the arg
// lets the scheduler fill by resources: VGPR ~112-128 -> 4 waves/SIMD ->
// 4 blocks/CU of fully independent waves, which is what the direct-L2 B reads
// need to hide their ~200-500cyc latency (R14's MfmaUtil collapse 16.5->10.4
// was that latency exposed at 2 waves/SIMD). Scale-folded: bare exp2 epilogue.
__global__ __launch_bounds__(256)
void gram_sym(const u8* __restrict__ Mf8, float* __restrict__ rsum) {
  const int t = threadIdx.x;
  const int lane = t & 63, wave = t >> 6;
  const int wm = (wave >> 1) * 64, wn = (wave & 1) * 64;
  const int fr = lane >> 4, fc = lane & 15;

  // ---- strip mapping (band closed form), long strips dispatched first ----
  int f = 2111 - blockIdx.x;
  int b = 0;
  while (f >= 2 * (b + 1) * (b + 2)) ++b;
  int rem = f - 2 * b * (b + 1);
  int r = rem / (b + 1);
  int q = rem - r * (b + 1);
  int k = 4 * b + 1 + r;
  const int i_t = 128 - k;
  const int jt0 = i_t + 4 * q;
  const int L = min(4, k - 4 * q);
  const int i0 = i_t * 128;

  // gather A fragments into registers (L2/L3-resident; once per strip)
  i32x8 afr[4][2];
  {
    const u8* Ag = Mf8 + (size_t)i0 * 256;
#pragma unroll
    for (int mi = 0; mi < 4; ++mi) {
      const u8* rp = Ag + (size_t)(wm + mi * 16 + fc) * 256 + fr * 32;
#pragma unroll
      for (int kb = 0; kb < 2; ++kb) {
        int4 lo = *(const int4*)(rp + kb * 128);
        int4 hi = *(const int4*)(rp + kb * 128 + 16);
        afr[mi][kb] = (i32x8){lo.x, lo.y, lo.z, lo.w, hi.x, hi.y, hi.z, hi.w};
      }
    }
  }

  float rowacc[4][4];
  float colps[4][4];               // [tile][ni], flushed at strip end
#pragma unroll
  for (int a = 0; a < 4; a++)
#pragma unroll
    for (int rr = 0; rr < 4; rr++) { rowacc[a][rr] = 0.f; colps[a][rr] = 0.f; }

  // per-lane B base within a tile: row (wn + ni*16 + fc), bytes kb*128+fr*32
  const u8* Bbase = Mf8 + (size_t)jt0 * 32768 + (size_t)(wn + fc) * 256 + fr * 32;

#pragma unroll
  for (int jt = 0; jt < 4; ++jt) {
    if (jt < L) {                  // uniform guard (L uniform per block)
      const u8* Bt = Bbase + (size_t)jt * 32768;

      f32x4 acc[4][4];
#pragma unroll
      for (int a = 0; a < 4; a++)
#pragma unroll
        for (int bb = 0; bb < 4; bb++) acc[a][bb] = (f32x4){0.f, 0.f, 0.f, 0.f};

#pragma unroll
      for (int kb = 0; kb < 2; ++kb) {
        i32x8 bfrag[4];
#pragma unroll
        for (int ni = 0; ni < 4; ++ni) {
          const u8* rp = Bt + ni * 4096 + kb * 128;   // ni*16 rows * 256 B
          int4 lo = *(const int4*)rp;
          int4 hi = *(const int4*)(rp + 16);
          bfrag[ni] = (i32x8){lo.x, lo.y, lo.z, lo.w, hi.x, hi.y, hi.z, hi.w};
        }
#pragma unroll
        for (int mi = 0; mi < 4; mi++)
#pragma unroll
          for (int ni = 0; ni < 4; ni++)
            acc[mi][ni] = __builtin_amdgcn_mfma_scale_f32_16x16x128_f8f6f4(
                afr[mi][kb], bfrag[ni], acc[mi][ni], 0, 0, 0, 0x7F, 0, 0x7F);
      }

      // tile epilogue: bare exp2 (scale pre-folded), register-only accumulation
#pragma unroll
      for (int mi = 0; mi < 4; mi++) {
#pragma unroll
        for (int ni = 0; ni < 4; ni++) {
          float e0 = hw_exp2(acc[mi][ni][0]);
          float e1 = hw_exp2(acc[mi][ni][1]);
          float e2 = hw_exp2(acc[mi][ni][2]);
          float e3 = hw_exp2(acc[mi][ni][3]);
          rowacc[mi][0] += e0; rowacc[mi][1] += e1;
          rowacc[mi][2] += e2; rowacc[mi][3] += e3;
          colps[jt][ni] += e0 + e1 + e2 + e3;
        }
      }
    }
  }

  // ---- strip-end flush: all global atomics live here ----
  // column partials (skip the diagonal tile: its transpose IS the row sum)
#pragma unroll
  for (int jt = 0; jt < 4; ++jt) {
    if (jt < L) {
      const int j_t = jt0 + jt;
      if (j_t != i_t) {
        const int j0 = j_t * 128;
#pragma unroll
        for (int ni = 0; ni < 4; ni++) {
          float v = colps[jt][ni];
          v += __shfl_xor(v, 16, 64);
          v += __shfl_xor(v, 32, 64);
          if (fr == 0) atomicAdd(&rsum[j0 + wn + ni * 16 + fc], v);
        }
      }
    }
  }

  // row sums: reduce across the 16 fc lanes, one atomic set
#pragma unroll
  for (int mi = 0; mi < 4; mi++) {
#pragma unroll
    for (int rr = 0; rr < 4; rr++) {
      float v = rowacc[mi][rr];
#pragma unroll
      for (int off = 1; off < 16; off <<= 1) v += __shfl_xor(v, off, 16);
      rowacc[mi][rr] = v;
    }
  }
  if (fc == 0) {
#pragma unroll
    for (int mi = 0; mi < 4; mi++) {
      int rbase = i0 + wm + mi * 16 + fr * 4;
      atomicAdd(&rsum[rbase + 0], rowacc[mi][0]);
      atomicAdd(&rsum[rbase + 1], rowacc[mi][1]);
      atomicAdd(&rsum[rbase + 2], rowacc[mi][2]);
      atomicAdd(&rsum[rbase + 3], rowacc[mi][3]);
    }
  }
}

// ---------------- final loss (4 rows / block), scaled-fp8 diagonal -----------
// (R15 verbatim: f = exp2(dot_m); self-term = exp2(snorm); log f12 = dot*ln2)
__global__ void final_loss(const u8* __restrict__ Mf8, const float* __restrict__ rsum,
                           const float* __restrict__ snorm, float* __restrict__ out) {
  int i = blockIdx.x * 4 + (threadIdx.x >> 6);
  int lane = threadIdx.x & 63;
  unsigned int ua = ((const unsigned int*)(Mf8 + (size_t)i * 256))[lane];
  unsigned int ub = ((const unsigned int*)(Mf8 + (size_t)(Nn + i) * 256))[lane];
  float d = 0.f;
#pragma unroll
  for (int e = 0; e < 4; ++e) {
    __hip_fp8_e4m3 qa, qb;
    qa.__x = (ua >> (8 * e)) & 0xFF;
    qb.__x = (ub >> (8 * e)) & 0xFF;
    d += (float)qa * (float)qb;
  }
#pragma unroll
  for (int off = 32; off; off >>= 1) d += __shfl_xor(d, off, 64);
  if (lane == 0) {
    float den1 = rsum[i] - hw_exp2(snorm[i]);
    float den2 = rsum[Nn + i] - hw_exp2(snorm[Nn + i]);
    out[i] = 0.5f * (logf(den1) + logf(den2)) - d * LN2f;
  }
}

extern "C" void kernel_launch(void* const* d_in, const int* in_sizes, int n_in,
                              void* d_out, int out_size, void* d_ws, size_t ws_size,
                              hipStream_t stream) {
  const float* z1 = (const float*)d_in[0];
  const float* z2 = (const float*)d_in[1];
  const float* W1 = (const float*)d_in[2];
  const float* b1 = (const float*)d_in[3];
  const float* W2 = (const float*)d_in[4];
  const float* b2 = (const float*)d_in[5];
  float* out = (float*)d_out;

  char* ws = (char*)d_ws;
  u8*     Mf8   = (u8*)(ws);                           // 4 MB
  float*  rsum  = (float*)(ws + (4u << 20));           // 64 KB
  float*  snorm = (float*)(ws + (4u << 20) + 65536);   // 64 KB
  __bf16* Wb    = (__bf16*)(ws + (4u << 20) + 131072); // 256 KB (bf16 W1|W2)

  // W f32 -> bf16 once
  wcvt<<<64, 256, 0, stream>>>(W1, W2, Wb);

  // fused MLP (both layers) + normalize + scaled fp8 emit + snorm + rsum zero
  mlp_norm<<<256, 256, 0, stream>>>(z1, z2, Wb, b1, b2, Mf8, snorm, rsum);

  // upper-triangle strips of <=4 tiles: 2112 blocks, long strips first
  gram_sym<<<2112, 256, 0, stream>>>(Mf8, rsum);

  final_loss<<<Nn / 4, 256, 0, stream>>>(Mf8, rsum, snorm, out);
}

// Round 17
// 165.750 us; speedup vs baseline: 1.3659x; 1.3659x over previous
//
#include <hip/hip_runtime.h>
#include <hip/hip_bf16.h>
#include <hip/hip_fp8.h>
#include <stdint.h>

#define Nn 8192
#define TWO_N 16384
#define INV_TAU 2.0f
// exp(x/TAU) = exp2(x * 2.885390); sqrt(2.885390) is folded into the stored
// fp8 vectors so the Gram epilogue is a bare exp2 (no per-element mul).
#define SQRT_E2S 1.6986436f      /* sqrt(2.885390081777927) */
#define LN2f 0.69314718f

typedef unsigned short u16;
typedef unsigned char u8;
typedef __bf16 bf16x8 __attribute__((ext_vector_type(8)));
typedef float f32x4 __attribute__((ext_vector_type(4)));
typedef int i32x8 __attribute__((ext_vector_type(8)));

typedef const __attribute__((address_space(1))) void* gas_ptr;
typedef __attribute__((address_space(3))) void* las_ptr;

__device__ __forceinline__ void async_copy16(const void* g, void* l) {
  __builtin_amdgcn_global_load_lds((gas_ptr)g, (las_ptr)l, 16, 0, 0);
}

// v_exp_f32: D = 2^S0 (hardware transcendental)
__device__ __forceinline__ float hw_exp2(float x) {
  return __builtin_amdgcn_exp2f(x);
}

// ---------------- W f32 -> bf16 pre-convert (once, ~256 KB out) -------------
__global__ __launch_bounds__(256)
void wcvt(const float* __restrict__ W1, const float* __restrict__ W2,
          __bf16* __restrict__ Wb) {
  int i = (blockIdx.x * 256 + threadIdx.x) * 8;
  const float* s = (i < 65536) ? (W1 + i) : (W2 + (i - 65536));
  float4 a0 = *(const float4*)s, a1 = *(const float4*)(s + 4);
  bf16x8 v = {(__bf16)a0.x, (__bf16)a0.y, (__bf16)a0.z, (__bf16)a0.w,
              (__bf16)a1.x, (__bf16)a1.y, (__bf16)a1.z, (__bf16)a1.w};
  *(bf16x8*)&Wb[i] = v;
}

// ---------------- fused MLP + normalize + SCALED fp8 emit --------------------
// (R15 verbatim -- verified: emitted fp8 = n * SQRT_E2S, snorm = ||m||^2)
__global__ __launch_bounds__(256)
void mlp_norm(const float* __restrict__ z1, const float* __restrict__ z2,
              const __bf16* __restrict__ Wb, const float* __restrict__ b1,
              const float* __restrict__ b2,
              u8* __restrict__ Mf8, float* __restrict__ snorm,
              float* __restrict__ rsum) {
  __shared__ __bf16 sZ[64 * 64];    // 8 KB  (layer1 A; reduce scratch later)
  __shared__ __bf16 sW[256 * 64];   // 32 KB (W chunk, both layers)
  __shared__ __bf16 sH[64 * 256];   // 32 KB (H1, full K for layer 2)
  const int bx = blockIdx.x;
  const int i0 = bx * 64;
  const float* Zsrc = (bx < 128) ? (z1 + (size_t)i0 * 256)
                                 : (z2 + (size_t)(i0 - Nn) * 256);
  const int t = threadIdx.x;
  const int lane = t & 63, wave = t >> 6;
  const int wn = wave * 64;
  const int fr = lane >> 4, fc = lane & 15;
  const int sw = fc & 7;

  const __bf16* Wb1 = Wb;
  const __bf16* Wb2 = Wb + 65536;

  if (t < 64) rsum[i0 + t] = 0.f;

  f32x4 acc[4][4];
#pragma unroll
  for (int a = 0; a < 4; a++)
#pragma unroll
    for (int b = 0; b < 4; b++) acc[a][b] = (f32x4){0.f, 0.f, 0.f, 0.f};

  // ---- layer 1 ----
  for (int k0 = 0; k0 < 256; k0 += 64) {
    __syncthreads();
#pragma unroll
    for (int it = 0; it < 8; ++it) {               // W1: 2048 granules, async DMA
      int c = t + 256 * it;
      int row = c >> 3, g = (c & 7) ^ (row & 7);
      async_copy16(Wb1 + (size_t)row * 256 + k0 + g * 8, (void*)&sW[c * 8]);
    }
#pragma unroll
    for (int it = 0; it < 2; ++it) {               // Z: 512 granules (convert)
      int c = t + 256 * it;
      int row = c >> 3, g = (c & 7) ^ (row & 7);
      const float* s = Zsrc + (size_t)row * 256 + k0 + g * 8;
      float4 a0 = *(const float4*)s, a1 = *(const float4*)(s + 4);
      bf16x8 v = {(__bf16)a0.x, (__bf16)a0.y, (__bf16)a0.z, (__bf16)a0.w,
                  (__bf16)a1.x, (__bf16)a1.y, (__bf16)a1.z, (__bf16)a1.w};
      *(bf16x8*)&sZ[c * 8] = v;
    }
    __syncthreads();
#pragma unroll
    for (int ks = 0; ks < 2; ++ks) {
      bf16x8 af[4], bfr[4];
#pragma unroll
      for (int mi = 0; mi < 4; mi++)
        af[mi] = *(const bf16x8*)&sZ[(mi * 16 + fc) * 64 + (((ks * 4 + fr) ^ sw) * 8)];
#pragma unroll
      for (int ni = 0; ni < 4; ni++)
        bfr[ni] = *(const bf16x8*)&sW[(wn + ni * 16 + fc) * 64 + (((ks * 4 + fr) ^ sw) * 8)];
#pragma unroll
      for (int mi = 0; mi < 4; mi++)
#pragma unroll
        for (int ni = 0; ni < 4; ni++)
          acc[mi][ni] = __builtin_amdgcn_mfma_f32_16x16x32_bf16(af[mi], bfr[ni], acc[mi][ni], 0, 0, 0);
    }
  }

  // layer-1 epilogue: bias + elu -> bf16 into sH (granule-xor swizzled rows)
  {
    float bv[4];
#pragma unroll
    for (int ni = 0; ni < 4; ni++) bv[ni] = b1[wn + ni * 16 + fc];
#pragma unroll
    for (int mi = 0; mi < 4; mi++)
#pragma unroll
      for (int ni = 0; ni < 4; ni++) {
        int col = wn + ni * 16 + fc;
        int gc = col >> 3;
#pragma unroll
        for (int r = 0; r < 4; r++) {
          int row = mi * 16 + fr * 4 + r;
          float v = acc[mi][ni][r] + bv[ni];
          v = v > 0.f ? v : (__expf(v) - 1.f);
          int pos = (gc & 24) | ((gc & 7) ^ (row & 7));
          sH[row * 256 + pos * 8 + (col & 7)] = (__bf16)v;
          acc[mi][ni][r] = 0.f;
        }
      }
  }

  // ---- layer 2 (A = sH, resident full-K) ----
  for (int k0 = 0; k0 < 256; k0 += 64) {
    __syncthreads();   // also guarantees: all sH writes done before first read
#pragma unroll
    for (int it = 0; it < 8; ++it) {               // W2: 2048 granules, async DMA
      int c = t + 256 * it;
      int row = c >> 3, g = (c & 7) ^ (row & 7);
      async_copy16(Wb2 + (size_t)row * 256 + k0 + g * 8, (void*)&sW[c * 8]);
    }
    __syncthreads();
    const int kgb = k0 >> 3;
#pragma unroll
    for (int ks = 0; ks < 2; ++ks) {
      bf16x8 af[4], bfr[4];
#pragma unroll
      for (int mi = 0; mi < 4; mi++)
        af[mi] = *(const bf16x8*)&sH[(mi * 16 + fc) * 256 + (kgb + (((ks * 4 + fr) ^ sw))) * 8];
#pragma unroll
      for (int ni = 0; ni < 4; ni++)
        bfr[ni] = *(const bf16x8*)&sW[(wn + ni * 16 + fc) * 64 + (((ks * 4 + fr) ^ sw) * 8)];
#pragma unroll
      for (int mi = 0; mi < 4; mi++)
#pragma unroll
        for (int ni = 0; ni < 4; ni++)
          acc[mi][ni] = __builtin_amdgcn_mfma_f32_16x16x32_bf16(af[mi], bfr[ni], acc[mi][ni], 0, 0, 0);
    }
  }

  // ---- epilogue: bias, cross-wave row-norm, SCALED fp8 emit, snorm ----
  float bv[4];
#pragma unroll
  for (int ni = 0; ni < 4; ni++) bv[ni] = b2[wn + ni * 16 + fc];

  __syncthreads();                 // sZ dead; reuse as reduce scratch
  float* red = (float*)sZ;         // [64 rows][4 waves]
  float* red2 = red + 256;

#pragma unroll
  for (int mi = 0; mi < 4; mi++) {
    float ssq[4] = {0.f, 0.f, 0.f, 0.f};
#pragma unroll
    for (int ni = 0; ni < 4; ni++)
#pragma unroll
      for (int r = 0; r < 4; r++) {
        float v = acc[mi][ni][r] + bv[ni];
        acc[mi][ni][r] = v;
        ssq[r] += v * v;
      }
#pragma unroll
    for (int r = 0; r < 4; r++) {
      float v = ssq[r];
#pragma unroll
      for (int off = 1; off < 16; off <<= 1) v += __shfl_xor(v, off, 16);
      if (fc == 0) red[(mi * 16 + fr * 4 + r) * 4 + wave] = v;
    }
  }
  __syncthreads();

#pragma unroll
  for (int mi = 0; mi < 4; mi++) {
    float ssq2[4] = {0.f, 0.f, 0.f, 0.f};
#pragma unroll
    for (int r = 0; r < 4; r++) {
      int row = mi * 16 + fr * 4 + r;
      float ss = red[row * 4] + red[row * 4 + 1] + red[row * 4 + 2] + red[row * 4 + 3];
      float rn = SQRT_E2S / fmaxf(sqrtf(ss), 1e-12f);   // scale folded here
#pragma unroll
      for (int ni = 0; ni < 4; ni++) {
        float v = acc[mi][ni][r] * rn;
        __hip_fp8_e4m3 q(v);
        Mf8[(size_t)(i0 + row) * 256 + wn + ni * 16 + fc] = q.__x;
        float fv = (float)q;
        ssq2[r] += fv * fv;                              // snorm = ||m||^2
      }
    }
#pragma unroll
    for (int r = 0; r < 4; r++) {
      float v = ssq2[r];
#pragma unroll
      for (int off = 1; off < 16; off <<= 1) v += __shfl_xor(v, off, 16);
      if (fc == 0) red2[(mi * 16 + fr * 4 + r) * 4 + wave] = v;
    }
  }
  __syncthreads();
  if (t < 64)
    snorm[i0 + t] = red2[t * 4] + red2[t * 4 + 1] + red2[t * 4 + 2] + red2[t * 4 + 3];
}

// ---------------- symmetric Gram, MX fp8 K=128, A-in-regs, B dbuf ------------
// (R15 verbatim -- session-best 82.5 us. Structure at its measured floor:
//  unified VGPR+AGPR footprint (124+64=188/wave) pins residency at 2 waves/
//  SIMD; dbuf+barrier pipeline beats single-buffer/K-half/no-LDS/8-wave/
//  fused variants (R1/R5/R7/R9-R14/R16 all measured worse); atomics at strip
//  end; bare-exp2 epilogue interleaved between kb1 MFMA groups.)
__global__ __launch_bounds__(256, 2)
void gram_sym(const u8* __restrict__ Mf8, float* __restrict__ rsum) {
  __shared__ u8 sB8[2][128 * 256];   // 2 x 32 KB
  const int t = threadIdx.x;
  const int lane = t & 63, wave = t >> 6;
  const int wm = (wave >> 1) * 64, wn = (wave & 1) * 64;
  const int fr = lane >> 4, fc = lane & 15;

  // ---- strip mapping (band closed form), long strips dispatched first ----
  int f = 2111 - blockIdx.x;
  int b = 0;
  while (f >= 2 * (b + 1) * (b + 2)) ++b;
  int rem = f - 2 * b * (b + 1);
  int r = rem / (b + 1);
  int q = rem - r * (b + 1);
  int k = 4 * b + 1 + r;
  const int i_t = 128 - k;
  const int jt0 = i_t + 4 * q;
  const int L = min(4, k - 4 * q);
  const int i0 = i_t * 128;

  // stage B(tile 0) into buffer 0
  {
    const u8* Bg = Mf8 + (size_t)jt0 * 128 * 256;
#pragma unroll
    for (int it = 0; it < 8; ++it) {
      int c = t + 256 * it;
      int row = c >> 4, slot = c & 15;
      int g = slot ^ (row & 15);
      async_copy16(Bg + (size_t)row * 256 + g * 16, (void*)&sB8[0][c * 16]);
    }
  }

  // gather A fragments into registers (L2/L3-resident; once per strip)
  i32x8 afr[4][2];
  {
    const u8* Ag = Mf8 + (size_t)i0 * 256;
#pragma unroll
    for (int mi = 0; mi < 4; ++mi) {
      const u8* rp = Ag + (size_t)(wm + mi * 16 + fc) * 256 + fr * 32;
#pragma unroll
      for (int kb = 0; kb < 2; ++kb) {
        int4 lo = *(const int4*)(rp + kb * 128);
        int4 hi = *(const int4*)(rp + kb * 128 + 16);
        afr[mi][kb] = (i32x8){lo.x, lo.y, lo.z, lo.w, hi.x, hi.y, hi.z, hi.w};
      }
    }
  }

  float rowacc[4][4];
  float colps[4][4];               // [tile][ni], flushed at strip end
  f32x4 acc[4][4];                 // persists across tiles; re-zeroed in EPI
#pragma unroll
  for (int a = 0; a < 4; a++)
#pragma unroll
    for (int rr = 0; rr < 4; rr++) {
      rowacc[a][rr] = 0.f; colps[a][rr] = 0.f;
      acc[a][rr] = (f32x4){0.f, 0.f, 0.f, 0.f};
    }

  // epilogue for one mi group: bare exp2 (scale pre-folded into fp8 data) +
  // row/col accumulate + acc re-zero. Interleaved between kb1 MFMA groups.
#define EPI(m_, jt_)                                                      \
  {                                                                       \
    _Pragma("unroll")                                                     \
    for (int ni_ = 0; ni_ < 4; ++ni_) {                                   \
      float e0 = hw_exp2(acc[m_][ni_][0]);                                \
      float e1 = hw_exp2(acc[m_][ni_][1]);                                \
      float e2 = hw_exp2(acc[m_][ni_][2]);                                \
      float e3 = hw_exp2(acc[m_][ni_][3]);                                \
      rowacc[m_][0] += e0; rowacc[m_][1] += e1;                           \
      rowacc[m_][2] += e2; rowacc[m_][3] += e3;                           \
      colps[jt_][ni_] += e0 + e1 + e2 + e3;                               \
      acc[m_][ni_] = (f32x4){0.f, 0.f, 0.f, 0.f};                         \
    }                                                                     \
  }

#pragma unroll
  for (int jt = 0; jt < 4; ++jt) {
    if (jt < L) {                  // block-uniform guard (L uniform)
      const int j_t = jt0 + jt;
      const u8* sB = &sB8[jt & 1][0];

      __syncthreads();   // drains B(jt) staging (issued >=1 tile ago; landed)

      if (jt + 1 < L) {  // prefetch B(jt+1) behind the barrier
        const u8* Bg = Mf8 + (size_t)(j_t + 1) * 128 * 256;
        u8* dst = &sB8[(jt + 1) & 1][0];
#pragma unroll
        for (int it = 0; it < 8; ++it) {
          int c = t + 256 * it;
          int row = c >> 4, slot = c & 15;
          int g = slot ^ (row & 15);
          async_copy16(Bg + (size_t)row * 256 + g * 16, (void*)&dst[c * 16]);
        }
      }

      // ---- kb = 0: read frags, issue all 16 MFMA ----
      i32x8 b0[4];
#pragma unroll
      for (int ni = 0; ni < 4; ++ni) {
        const u8* base = sB + (wn + ni * 16 + fc) * 256;
        int g0 = fr * 2;
        int4 lo = *(const int4*)(base + ((g0 ^ fc) * 16));
        int4 hi = *(const int4*)(base + (((g0 + 1) ^ fc) * 16));
        b0[ni] = (i32x8){lo.x, lo.y, lo.z, lo.w, hi.x, hi.y, hi.z, hi.w};
      }
#pragma unroll
      for (int mi = 0; mi < 4; mi++)
#pragma unroll
        for (int ni = 0; ni < 4; ni++)
          acc[mi][ni] = __builtin_amdgcn_mfma_scale_f32_16x16x128_f8f6f4(
              afr[mi][0], b0[ni], acc[mi][ni], 0, 0, 0, 0x7F, 0, 0x7F);

      // ---- kb = 1 frags ----
      i32x8 b1[4];
#pragma unroll
      for (int ni = 0; ni < 4; ++ni) {
        const u8* base = sB + (wn + ni * 16 + fc) * 256;
        int g0 = 8 + fr * 2;
        int4 lo = *(const int4*)(base + ((g0 ^ fc) * 16));
        int4 hi = *(const int4*)(base + (((g0 + 1) ^ fc) * 16));
        b1[ni] = (i32x8){lo.x, lo.y, lo.z, lo.w, hi.x, hi.y, hi.z, hi.w};
      }

      // ---- kb = 1: per-mi groups with interleaved epilogue ----
#pragma unroll
      for (int ni = 0; ni < 4; ni++)
        acc[0][ni] = __builtin_amdgcn_mfma_scale_f32_16x16x128_f8f6f4(
            afr[0][1], b1[ni], acc[0][ni], 0, 0, 0, 0x7F, 0, 0x7F);
#pragma unroll
      for (int ni = 0; ni < 4; ni++)
        acc[1][ni] = __builtin_amdgcn_mfma_scale_f32_16x16x128_f8f6f4(
            afr[1][1], b1[ni], acc[1][ni], 0, 0, 0, 0x7F, 0, 0x7F);
      EPI(0, jt)
#pragma unroll
      for (int ni = 0; ni < 4; ni++)
        acc[2][ni] = __builtin_amdgcn_mfma_scale_f32_16x16x128_f8f6f4(
            afr[2][1], b1[ni], acc[2][ni], 0, 0, 0, 0x7F, 0, 0x7F);
      EPI(1, jt)
#pragma unroll
      for (int ni = 0; ni < 4; ni++)
        acc[3][ni] = __builtin_amdgcn_mfma_scale_f32_16x16x128_f8f6f4(
            afr[3][1], b1[ni], acc[3][ni], 0, 0, 0, 0x7F, 0, 0x7F);
      EPI(2, jt)
      EPI(3, jt)
    }
  }
#undef EPI

  // ---- strip-end flush: all global atomics live here, no barrier after ----
  // column partials (skip the diagonal tile: its transpose IS the row sum)
#pragma unroll
  for (int jt = 0; jt < 4; ++jt) {
    if (jt < L) {
      const int j_t = jt0 + jt;
      if (j_t != i_t) {
        const int j0 = j_t * 128;
#pragma unroll
        for (int ni = 0; ni < 4; ni++) {
          float v = colps[jt][ni];
          v += __shfl_xor(v, 16, 64);
          v += __shfl_xor(v, 32, 64);
          if (fr == 0) atomicAdd(&rsum[j0 + wn + ni * 16 + fc], v);
        }
      }
    }
  }

  // row sums: reduce across the 16 fc lanes, one atomic set
#pragma unroll
  for (int mi = 0; mi < 4; mi++) {
#pragma unroll
    for (int rr = 0; rr < 4; rr++) {
      float v = rowacc[mi][rr];
#pragma unroll
      for (int off = 1; off < 16; off <<= 1) v += __shfl_xor(v, off, 16);
      rowacc[mi][rr] = v;
    }
  }
  if (fc == 0) {
#pragma unroll
    for (int mi = 0; mi < 4; mi++) {
      int rbase = i0 + wm + mi * 16 + fr * 4;
      atomicAdd(&rsum[rbase + 0], rowacc[mi][0]);
      atomicAdd(&rsum[rbase + 1], rowacc[mi][1]);
      atomicAdd(&rsum[rbase + 2], rowacc[mi][2]);
      atomicAdd(&rsum[rbase + 3], rowacc[mi][3]);
    }
  }
}

// ---------------- final loss (4 rows / block), scaled-fp8 diagonal -----------
// (R15 verbatim: f = exp2(dot_m); self-term = exp2(snorm); log f12 = dot*ln2)
__global__ void final_loss(const u8* __restrict__ Mf8, const float* __restrict__ rsum,
                           const float* __restrict__ snorm, float* __restrict__ out) {
  int i = blockIdx.x * 4 + (threadIdx.x >> 6);
  int lane = threadIdx.x & 63;
  unsigned int ua = ((const unsigned int*)(Mf8 + (size_t)i * 256))[lane];
  unsigned int ub = ((const unsigned int*)(Mf8 + (size_t)(Nn + i) * 256))[lane];
  float d = 0.f;
#pragma unroll
  for (int e = 0; e < 4; ++e) {
    __hip_fp8_e4m3 qa, qb;
    qa.__x = (ua >> (8 * e)) & 0xFF;
    qb.__x = (ub >> (8 * e)) & 0xFF;
    d += (float)qa * (float)qb;
  }
#pragma unroll
  for (int off = 32; off; off >>= 1) d += __shfl_xor(d, off, 64);
  if (lane == 0) {
    float den1 = rsum[i] - hw_exp2(snorm[i]);
    float den2 = rsum[Nn + i] - hw_exp2(snorm[Nn + i]);
    out[i] = 0.5f * (logf(den1) + logf(den2)) - d * LN2f;
  }
}

extern "C" void kernel_launch(void* const* d_in, const int* in_sizes, int n_in,
                              void* d_out, int out_size, void* d_ws, size_t ws_size,
                              hipStream_t stream) {
  const float* z1 = (const float*)d_in[0];
  const float* z2 = (const float*)d_in[1];
  const float* W1 = (const float*)d_in[2];
  const float* b1 = (const float*)d_in[3];
  const float* W2 = (const float*)d_in[4];
  const float* b2 = (const float*)d_in[5];
  float* out = (float*)d_out;

  char* ws = (char*)d_ws;
  u8*     Mf8   = (u8*)(ws);                           // 4 MB
  float*  rsum  = (float*)(ws + (4u << 20));           // 64 KB
  float*  snorm = (float*)(ws + (4u << 20) + 65536);   // 64 KB
  __bf16* Wb    = (__bf16*)(ws + (4u << 20) + 131072); // 256 KB (bf16 W1|W2)

  // W f32 -> bf16 once
  wcvt<<<64, 256, 0, stream>>>(W1, W2, Wb);

  // fused MLP (both layers) + normalize + scaled fp8 emit + snorm + rsum zero
  mlp_norm<<<256, 256, 0, stream>>>(z1, z2, Wb, b1, b2, Mf8, snorm, rsum);

  // upper-triangle strips of <=4 tiles: 2112 blocks, long strips first
  gram_sym<<<2112, 256, 0, stream>>>(Mf8, rsum);

  final_loss<<<Nn / 4, 256, 0, stream>>>(Mf8, rsum, snorm, out);
}